// Round 2
// baseline (181.379 us; speedup 1.0000x reference)
//
#include <hip/hip_runtime.h>
#include <hip/hip_cooperative_groups.h>

namespace cg = cooperative_groups;

// ForwardDistance: out[b,n,m] = sum_a agg[a] * tanh(datalin[b,n,a] + critlin[b,m,a])
// tanh(x+y) = 1 - 2/(1 + e^{2x} e^{2y})
// R13: dispatch-count attack. R12 (major restructure) was NULL (-0.6us) -> measured
// time is dominated by fixed per-dispatch overhead (fill + 3 kernel launches + gaps),
// not kernel internals (kernel arithmetic floor ~30us total). Fuse all 3 kernels into
// ONE cooperative kernel; two grid.sync()s replace the two kernel boundaries.
// 256 blocks x 1024 thr, 140 KB LDS union -> exactly 1 block/CU x 256 CUs (valid coop grid).
//  P0: W[k][a] fp32 -> wt[a][k] bf16 (2MB, NT stores), 64k x 16a slice per block.
//  P1: proj MFMA 64 rows x 64 a per block (16 waves, 1 acc each), exp2 epilogue -> eplanes.
//  P2: tanh-reduce, R12 body verbatim (4 a-quarters, quad-grouped rcp, f32x2 packed).

#define A_DIM 256
#define K_DIM 512
#define NROWS 2048   // rows per source (B*N == B*M)

typedef unsigned short ushort;
typedef __attribute__((ext_vector_type(4))) unsigned short us4;
typedef __attribute__((ext_vector_type(8))) unsigned short us8;
typedef __attribute__((ext_vector_type(8))) short short8;   // bf16x8 MFMA frag
typedef __attribute__((ext_vector_type(4))) float f32x4;    // MFMA acc / NT stores
typedef __attribute__((ext_vector_type(2))) float f32x2;    // packed fp32

__device__ inline ushort f2bf(float x) {    // round-to-nearest-even bf16
    union { float f; unsigned u; } v; v.f = x;
    unsigned r = v.u + 0x7FFFu + ((v.u >> 16) & 1u);
    return (ushort)(r >> 16);
}
__device__ inline float bf2f(ushort h) {
    union { unsigned u; float f; } v; v.u = ((unsigned)h) << 16; return v.f;
}
__device__ inline unsigned pack2bf(float lo, float hi) {
    return (unsigned)f2bf(lo) | ((unsigned)f2bf(hi) << 16);
}
__device__ inline f32x2 fma2(f32x2 a, f32x2 b, f32x2 c) {
    return __builtin_elementwise_fma(a, b, c);
}

__global__ __launch_bounds__(1024) void fused_fd_kernel(
    const float* __restrict__ data, const float* __restrict__ crit,
    const float* __restrict__ Wl, const float* __restrict__ bl,
    const float* __restrict__ Wr, const float* __restrict__ br,
    const float* __restrict__ agg,
    ushort* __restrict__ wt, ushort* __restrict__ eplanes,
    float* __restrict__ out)
{
    __shared__ __align__(16) union {
        float tile[64][17];                                   // P0: 4.3 KB
        ushort Ws[64][520];                                   // P1: 66.6 KB (pad 520)
        struct { float et[4][64][68]; float ect[4][64][68];   // P2: 139.3 KB
                 float aggs[256]; } p2;                       //     +1 KB
    } sm;

    const int t   = threadIdx.x;
    const int bid = blockIdx.x;
    cg::grid_group grid = cg::this_grid();

    // ================= P0: W transpose+cast (2 src x 8 kt x 16 at = 256 blocks) ====
    {
        const int at  = bid & 15;
        const int kt  = (bid >> 4) & 7;
        const int src = bid >> 7;
        const int a0 = at * 16, k0 = kt * 64;
        const float* W = src ? Wr : Wl;
        ushort* o = wt + (size_t)src * (A_DIM * K_DIM);

        const int k = t >> 4, ai = t & 15;                    // 64k x 16a, 1 elem/thread
        sm.tile[k][ai] = W[(size_t)(k0 + k) * A_DIM + a0 + ai];
        __syncthreads();
        const int a2 = t >> 6, kk = t & 63;                   // coalesced 128B/wave writes
        __builtin_nontemporal_store(f2bf(sm.tile[kk][a2]),
                                    o + (size_t)(a0 + a2) * K_DIM + k0 + kk);
    }
    grid.sync();

    // ================= P1: proj MFMA (64 rt x 4 ct = 256 blocks; 64 rows x 64 a) ===
    {
        const int rt  = bid & 63;        // consecutive bids share W tile / walk rows
        const int ct  = bid >> 6;
        const int src = rt >> 5;
        const int lr0 = (rt & 31) * 64;
        const int c0  = ct * 64;

        const float* X    = src ? crit : data;
        const float* bias = src ? br : bl;
        const ushort* Wt  = wt + (size_t)src * (A_DIM * K_DIM);
        ushort* E = eplanes + (size_t)src * ((size_t)A_DIM * NROWS);

        const int lane = t & 63;
        const int wid  = t >> 6;             // 16 waves: 4 (rows) x 4 (a-cols)
        const int wm   = wid >> 2, wn = wid & 3;
        const int quad = lane >> 4, l16 = lane & 15;

        const float* xrow = X + (size_t)(lr0 + wm * 16 + l16) * K_DIM + quad * 8;
        const int aloc = wn * 16 + l16;

        {   // stage Ws[a][0..511], 16 threads/row x 32 ushorts
            const int a  = t & 63;
            const int ks = (t >> 6) * 32;
            const ushort* s = Wt + (size_t)(c0 + a) * K_DIM + ks;
#pragma unroll
            for (int i = 0; i < 4; i++)
                *(us8*)&sm.Ws[a][ks + i * 8] = *(const us8*)(s + i * 8);
        }

        f32x4 acc = {0.f, 0.f, 0.f, 0.f};
        // 2-deep rolling A prefetch (issued before the barrier: independent of LDS)
        float4 pa0 = *(const float4*)(xrow);
        float4 pb0 = *(const float4*)(xrow + 4);
        float4 pa1 = *(const float4*)(xrow + 32);
        float4 pb1 = *(const float4*)(xrow + 36);

        __syncthreads();

#pragma unroll
        for (int s = 0; s < 16; s++) {
            float4 ca = pa0, cb = pb0;
            pa0 = pa1; pb0 = pb1;
            if (s < 14) {                 // keep 2 steps in flight
                pa1 = *(const float4*)(xrow + (s + 2) * 32);
                pb1 = *(const float4*)(xrow + (s + 2) * 32 + 4);
            }
            union { short8 s8; unsigned u[4]; } af;
            af.u[0] = pack2bf(ca.x, ca.y);
            af.u[1] = pack2bf(ca.z, ca.w);
            af.u[2] = pack2bf(cb.x, cb.y);
            af.u[3] = pack2bf(cb.z, cb.w);
            short8 b0 = *(const short8*)&sm.Ws[aloc][s * 32 + quad * 8];
            acc = __builtin_amdgcn_mfma_f32_16x16x32_bf16(af.s8, b0, acc, 0, 0, 0);
        }

        // epilogue: C/D layout col=lane&15 (a), row=quad*4+reg. NT bf16 stores.
        const float c2 = 2.8853900817779268f;    // 2*log2(e)
        const int a_col = c0 + wn * 16 + l16;
        const int row0  = lr0 + wm * 16 + quad * 4;
        const float bv = bias[a_col];
        us4 e0;
#pragma unroll
        for (int i = 0; i < 4; i++) {
            float v0 = (acc[i] + bv) * c2;
            v0 = fminf(fmaxf(v0, -15.f), 15.f);   // bounds q<=1+2^30 for rcp path
            e0[i] = f2bf(__builtin_amdgcn_exp2f(v0));
        }
        __builtin_nontemporal_store(e0, (us4*)(E + (size_t)a_col * NROWS + row0));
    }
    grid.sync();

    // ================= P2: tanh-reduce (8m x 8n x 4b = 256 blocks) =================
    {
        const int h  = t >> 8;               // a-quarter (a in [h*64, h*64+64))
        const int u  = t & 255;              // thread id within quarter
        const int m0 = (bid & 7) * 64;
        const int n0 = ((bid >> 3) & 7) * 64;
        const int b  = bid >> 6;

        const size_t PLANE = (size_t)A_DIM * NROWS;
        const ushort* Ed = eplanes;
        const ushort* Ec = eplanes + PLANE;
        const int row_n = b * 512 + n0;
        const int row_m = b * 512 + m0;

        const int tx = u & 15;               // m group (4 m's)
        const int ty = u >> 4;               // n group (4 n's)

        if (t < 256) sm.p2.aggs[t] = 2.0f * agg[t];

        f32x2 acc2[4][2];                    // [n i][m j-pair]
#pragma unroll
        for (int i = 0; i < 4; i++) { acc2[i][0] = (f32x2)0.f; acc2[i][1] = (f32x2)0.f; }
        float sagg = 0.f;

        const int aL = u >> 2;               // staging row 0..63
        const int qd = u & 3;                // staging quarter (16 cols each)

        float (*eth)[68]  = sm.p2.et[h];
        float (*ecth)[68] = sm.p2.ect[h];

        {   // single-shot staging: quarter h stages its 64 a-rows of both planes
            const size_t base = (size_t)(h * 64 + aL) * NROWS;
            us4 pn[4], pm[4];
#pragma unroll
            for (int r = 0; r < 4; r++) {
                pn[r] = *(const us4*)(Ed + base + row_n + qd * 16 + r * 4);
                pm[r] = *(const us4*)(Ec + base + row_m + qd * 16 + r * 4);
            }
#pragma unroll
            for (int r = 0; r < 4; r++) {
                float4 ev, cv;
                ev.x = bf2f(pn[r][0]); ev.y = bf2f(pn[r][1]);
                ev.z = bf2f(pn[r][2]); ev.w = bf2f(pn[r][3]);
                cv.x = bf2f(pm[r][0]); cv.y = bf2f(pm[r][1]);
                cv.z = bf2f(pm[r][2]); cv.w = bf2f(pm[r][3]);
                *(float4*)&eth [aL][qd * 16 + r * 4] = ev;
                *(float4*)&ecth[aL][qd * 16 + r * 4] = cv;
            }
        }
        __syncthreads();

        for (int qg = 0; qg < 16; qg++) {    // a-quads: one rcp per 4 a-terms
            const float4 ag = *(const float4*)&sm.p2.aggs[h * 64 + qg * 4];
            sagg += (ag.x + ag.y) + (ag.z + ag.w);
            float  en[4][4];                 // [a u][n i]
            f32x2  fm[4][2];                 // [a u][m j-pair]
#pragma unroll
            for (int v = 0; v < 4; v++) {
                float4 e4 = *(const float4*)&eth [qg * 4 + v][ty * 4];
                float4 f4 = *(const float4*)&ecth[qg * 4 + v][tx * 4];
                en[v][0] = e4.x; en[v][1] = e4.y; en[v][2] = e4.z; en[v][3] = e4.w;
                fm[v][0] = f32x2{f4.x, f4.y};
                fm[v][1] = f32x2{f4.z, f4.w};
            }
#pragma unroll
            for (int i = 0; i < 4; i++)
#pragma unroll
                for (int jp = 0; jp < 2; jp++) {
                    const f32x2 one = (f32x2)1.f;
                    f32x2 q0 = fma2((f32x2)en[0][i], fm[0][jp], one);
                    f32x2 q1 = fma2((f32x2)en[1][i], fm[1][jp], one);
                    f32x2 q2 = fma2((f32x2)en[2][i], fm[2][jp], one);
                    f32x2 q3 = fma2((f32x2)en[3][i], fm[3][jp], one);
                    f32x2 q01 = q0 * q1, q23 = q2 * q3;
                    f32x2 n01 = fma2((f32x2)ag.x, q1, (f32x2)ag.y * q0);
                    f32x2 n23 = fma2((f32x2)ag.z, q3, (f32x2)ag.w * q2);
                    f32x2 N   = fma2(n01, q23, n23 * q01);
                    f32x2 D   = q01 * q23;              // <= 2^121, no overflow
                    f32x2 r;
                    r.x = __builtin_amdgcn_rcpf(D.x);
                    r.y = __builtin_amdgcn_rcpf(D.y);
                    acc2[i][jp] = fma2(N, r, acc2[i][jp]);
                }
        }

        // partial_h = 0.5*sagg_h - acc_h ; 4-way merge via LDS (stride 17: conflict-free)
        const float base = 0.5f * sagg;
        float* xb = (float*)sm.p2.ect;       // reuse (3*256*17 floats = 52 KB < 69.6 KB)
        __syncthreads();                     // all LDS reads of et/ect complete
        if (h != 0) {
            float* w = xb + ((size_t)(h - 1) * 256 + u) * 17;
#pragma unroll
            for (int i = 0; i < 4; i++)
#pragma unroll
                for (int jp = 0; jp < 2; jp++) {
                    w[i * 4 + jp * 2 + 0] = base - acc2[i][jp].x;
                    w[i * 4 + jp * 2 + 1] = base - acc2[i][jp].y;
                }
        }
        __syncthreads();
        if (h == 0) {
            const float* x1 = xb + (size_t)u * 17;
            const float* x2 = xb + ((size_t)256 + u) * 17;
            const float* x3 = xb + ((size_t)512 + u) * 17;
#pragma unroll
            for (int i = 0; i < 4; i++) {
                f32x4 v;
                v.x = ((base - acc2[i][0].x) + x1[i * 4 + 0]) + (x2[i * 4 + 0] + x3[i * 4 + 0]);
                v.y = ((base - acc2[i][0].y) + x1[i * 4 + 1]) + (x2[i * 4 + 1] + x3[i * 4 + 1]);
                v.z = ((base - acc2[i][1].x) + x1[i * 4 + 2]) + (x2[i * 4 + 2] + x3[i * 4 + 2]);
                v.w = ((base - acc2[i][1].y) + x1[i * 4 + 3]) + (x2[i * 4 + 3] + x3[i * 4 + 3]);
                __builtin_nontemporal_store(v,
                    (f32x4*)(out + ((size_t)(b * 512 + n0 + ty * 4 + i) * 512) + m0 + tx * 4));
            }
        }
    }
}

extern "C" void kernel_launch(void* const* d_in, const int* in_sizes, int n_in,
                              void* d_out, int out_size, void* d_ws, size_t ws_size,
                              hipStream_t stream) {
    const float* data = (const float*)d_in[0];
    const float* crit = (const float*)d_in[1];
    const float* Wl   = (const float*)d_in[2];
    const float* bl   = (const float*)d_in[3];
    const float* Wr   = (const float*)d_in[4];
    const float* br   = (const float*)d_in[5];
    const float* agg  = (const float*)d_in[6];
    float* out = (float*)d_out;

    // ws layout: Ed bf16 [256][2048] (1 MB) | Ec (1 MB) | Wt bf16 2x[256][512] (0.5 MB)
    ushort* eplanes = (ushort*)d_ws;
    ushort* wt      = eplanes + 2 * (size_t)A_DIM * NROWS;

    void* args[] = { (void*)&data, (void*)&crit, (void*)&Wl, (void*)&bl,
                     (void*)&Wr, (void*)&br, (void*)&agg,
                     (void*)&wt, (void*)&eplanes, (void*)&out };
    hipLaunchCooperativeKernel((void*)fused_fd_kernel, dim3(256), dim3(1024),
                               args, 0, stream);
}

// Round 3
// 105.792 us; speedup vs baseline: 1.7145x; 1.7145x over previous
//
#include <hip/hip_runtime.h>

// ForwardDistance: out[b,n,m] = sum_a agg[a] * tanh(datalin[b,n,a] + critlin[b,m,a])
// tanh(x+y) = 1 - 2/(1 + e^{2x} e^{2y})
// R14: dispatch-boundary reduction WITHOUT cooperative sync (R13 showed grid.sync
// costs ~30us each + coop launch adds ~44us host overhead -> reverted).
// 3 dispatches -> 2: W-transpose folded into proj. Each proj block reads its fp32
// W-slice [512k][64a] directly (L2-resident across 64 sharing blocks), casts+
// transposes into LDS per 256-k chunk (Ws[64][264], 33.8 KB -> 4 blocks/CU,
// back to R11 occupancy). tanh kernel is R12-verbatim (proven).

#define A_DIM 256
#define K_DIM 512
#define NROWS 2048   // rows per source (B*N == B*M)

typedef unsigned short ushort;
typedef __attribute__((ext_vector_type(4))) unsigned short us4;
typedef __attribute__((ext_vector_type(8))) unsigned short us8;
typedef __attribute__((ext_vector_type(8))) short short8;   // bf16x8 MFMA frag
typedef __attribute__((ext_vector_type(4))) float f32x4;    // MFMA acc / NT stores
typedef __attribute__((ext_vector_type(2))) float f32x2;    // packed fp32

__device__ inline ushort f2bf(float x) {    // round-to-nearest-even bf16
    union { float f; unsigned u; } v; v.f = x;
    unsigned r = v.u + 0x7FFFu + ((v.u >> 16) & 1u);
    return (ushort)(r >> 16);
}
__device__ inline float bf2f(ushort h) {
    union { unsigned u; float f; } v; v.u = ((unsigned)h) << 16; return v.f;
}
__device__ inline unsigned pack2bf(float lo, float hi) {
    return (unsigned)f2bf(lo) | ((unsigned)f2bf(hi) << 16);
}
__device__ inline f32x2 fma2(f32x2 a, f32x2 b, f32x2 c) {
    return __builtin_elementwise_fma(a, b, c);
}

// ---- bf16 MFMA GEMM + exp2 epilogue -> Ed/Ec bf16 planes [a][row] ----
// Inline W transpose+cast: global fp32 W[k][a] -> LDS Ws[a][k-chunk] bf16, per chunk.
__global__ __launch_bounds__(256, 4) void proj_mfma_kernel(
    const float* __restrict__ data, const float* __restrict__ crit,
    const float* __restrict__ Wl, const float* __restrict__ bl,
    const float* __restrict__ Wr, const float* __restrict__ br,
    ushort* __restrict__ eplanes)
{
    __shared__ ushort Ws[64][264];   // [a][k-chunk 256], pad 264 (row 528B = 33x16B)

    const int t   = threadIdx.x;
    const int bid = blockIdx.x;
    const int ct  = bid >> 7;        // a-col tile (64): consecutive bids share W slice
    const int rt  = bid & 127;       // row tile (32 rows): contiguous per XCD
    const int src = rt >> 6;
    const int lr0 = (rt & 63) * 32;
    const int c0  = ct * 64;

    const float* X    = src ? crit : data;
    const float* bias = src ? br : bl;
    const float* W    = src ? Wr : Wl;
    ushort* E = eplanes + (size_t)src * ((size_t)A_DIM * NROWS);

    const int lane = t & 63;
    const int wid  = t >> 6;             // 4 waves: 2 (rows) x 2 (a-cols)
    const int wm   = wid >> 1, wn = wid & 1;
    const int quad = lane >> 4, l16 = lane & 15;

    const float* xrow = X + (size_t)(lr0 + wm * 16 + l16) * K_DIM + quad * 8;
    const int aloc0 = wn * 32 + l16;

    // transpose-stage lane decode: wave w covers chunk-local k in [w*64,(w+1)*64)
    const int kq = lane >> 4;            // 0..3
    const int aq = lane & 15;            // 0..15

    f32x4 acc0 = {0.f, 0.f, 0.f, 0.f}, acc1 = {0.f, 0.f, 0.f, 0.f};

    // 2-deep rolling A prefetch (independent of LDS staging)
    float4 pa0 = *(const float4*)(xrow);
    float4 pb0 = *(const float4*)(xrow + 4);
    float4 pa1 = *(const float4*)(xrow + 32);
    float4 pb1 = *(const float4*)(xrow + 36);

    for (int kc = 0; kc < 2; kc++) {     // two 256-k chunks
        __syncthreads();                 // prior chunk's Ws reads complete
        {   // stage+transpose chunk kc: W[kc*256 + klocal][c0 + a] -> Ws[a][klocal]
#pragma unroll
            for (int p = 0; p < 4; p++) {
                const int kb = wid * 64 + p * 16;             // chunk-local k base
                f32x4 v[4];
#pragma unroll
                for (int j = 0; j < 4; j++)
                    v[j] = *(const f32x4*)(W + (size_t)(kc * 256 + kb + kq * 4 + j) * A_DIM
                                             + c0 + aq * 4);
#pragma unroll
                for (int ai = 0; ai < 4; ai++) {
                    us4 o;
#pragma unroll
                    for (int j = 0; j < 4; j++) o[j] = f2bf(v[j][ai]);
                    *(us4*)&Ws[aq * 4 + ai][kb + kq * 4] = o;
                }
            }
        }
        __syncthreads();

#pragma unroll
        for (int ls = 0; ls < 8; ls++) {
            const int s = kc * 8 + ls;
            float4 ca = pa0, cb = pb0;
            pa0 = pa1; pb0 = pb1;
            if (s < 14) {                // keep 2 A-steps in flight
                pa1 = *(const float4*)(xrow + (s + 2) * 32);
                pb1 = *(const float4*)(xrow + (s + 2) * 32 + 4);
            }
            union { short8 s8; unsigned u[4]; } af;
            af.u[0] = pack2bf(ca.x, ca.y);
            af.u[1] = pack2bf(ca.z, ca.w);
            af.u[2] = pack2bf(cb.x, cb.y);
            af.u[3] = pack2bf(cb.z, cb.w);
            short8 b0 = *(const short8*)&Ws[aloc0     ][ls * 32 + quad * 8];
            short8 b1 = *(const short8*)&Ws[aloc0 + 16][ls * 32 + quad * 8];
            acc0 = __builtin_amdgcn_mfma_f32_16x16x32_bf16(af.s8, b0, acc0, 0, 0, 0);
            acc1 = __builtin_amdgcn_mfma_f32_16x16x32_bf16(af.s8, b1, acc1, 0, 0, 0);
        }
    }

    // epilogue: C/D layout col=lane&15 (a), row=quad*4+reg. NT bf16 stores.
    const float c2 = 2.8853900817779268f;    // 2*log2(e)
    const int a_col0 = c0 + wn * 32 + l16;
    const int a_col1 = a_col0 + 16;
    const int row0   = lr0 + wm * 16 + quad * 4;
    const float bv0 = bias[a_col0], bv1 = bias[a_col1];
    us4 e0, e1;
#pragma unroll
    for (int i = 0; i < 4; i++) {
        float v0 = (acc0[i] + bv0) * c2;
        float v1 = (acc1[i] + bv1) * c2;
        v0 = fminf(fmaxf(v0, -15.f), 15.f);   // bounds q<=1+2^30 for rcp path
        v1 = fminf(fmaxf(v1, -15.f), 15.f);
        e0[i] = f2bf(__builtin_amdgcn_exp2f(v0));
        e1[i] = f2bf(__builtin_amdgcn_exp2f(v1));
    }
    __builtin_nontemporal_store(e0, (us4*)(E + (size_t)a_col0 * NROWS + row0));
    __builtin_nontemporal_store(e1, (us4*)(E + (size_t)a_col1 * NROWS + row0));
}

// ---- tanh-reduce: 1024 thr, 64x64 tile, a-QUARTERS across wave groups,
//      single-shot staging, quad-grouped rcp + f32x2 packed math (R12-verbatim) ----
__global__ __launch_bounds__(1024) void tanh_reduce_kernel(
    const ushort* __restrict__ eplanes, const float* __restrict__ agg,
    float* __restrict__ out)
{
    __shared__ __align__(16) float et [4][64][68];   // [quarter][a][n]  69632 B
    __shared__ __align__(16) float ect[4][64][68];   // [quarter][a][m]  69632 B
    __shared__ __align__(16) float aggs[256];

    const int t  = threadIdx.x;
    const int h  = t >> 8;               // a-quarter (a in [h*64, h*64+64))
    const int u  = t & 255;              // thread id within quarter
    const int m0 = blockIdx.x * 64;
    const int n0 = blockIdx.y * 64;
    const int b  = blockIdx.z;

    const size_t PLANE = (size_t)A_DIM * NROWS;
    const ushort* Ed = eplanes;
    const ushort* Ec = eplanes + PLANE;
    const int row_n = b * 512 + n0;
    const int row_m = b * 512 + m0;

    const int tx = u & 15;               // m group (4 m's)
    const int ty = u >> 4;               // n group (4 n's)

    if (t < 256) aggs[t] = 2.0f * agg[t];

    f32x2 acc2[4][2];                    // [n i][m j-pair]
#pragma unroll
    for (int i = 0; i < 4; i++) { acc2[i][0] = (f32x2)0.f; acc2[i][1] = (f32x2)0.f; }
    float sagg = 0.f;

    const int aL = u >> 2;               // staging row 0..63
    const int qd = u & 3;                // staging quarter (16 cols each)

    float (*eth)[68]  = et[h];
    float (*ecth)[68] = ect[h];

    {   // single-shot staging: quarter h stages its 64 a-rows of both planes
        const size_t base = (size_t)(h * 64 + aL) * NROWS;
        us4 pn[4], pm[4];
#pragma unroll
        for (int r = 0; r < 4; r++) {
            pn[r] = *(const us4*)(Ed + base + row_n + qd * 16 + r * 4);
            pm[r] = *(const us4*)(Ec + base + row_m + qd * 16 + r * 4);
        }
#pragma unroll
        for (int r = 0; r < 4; r++) {
            float4 ev, cv;
            ev.x = bf2f(pn[r][0]); ev.y = bf2f(pn[r][1]);
            ev.z = bf2f(pn[r][2]); ev.w = bf2f(pn[r][3]);
            cv.x = bf2f(pm[r][0]); cv.y = bf2f(pm[r][1]);
            cv.z = bf2f(pm[r][2]); cv.w = bf2f(pm[r][3]);
            *(float4*)&eth [aL][qd * 16 + r * 4] = ev;
            *(float4*)&ecth[aL][qd * 16 + r * 4] = cv;
        }
    }
    __syncthreads();

    for (int qg = 0; qg < 16; qg++) {    // a-quads: one rcp per 4 a-terms
        const float4 ag = *(const float4*)&aggs[h * 64 + qg * 4];
        sagg += (ag.x + ag.y) + (ag.z + ag.w);
        float  en[4][4];                 // [a u][n i]
        f32x2  fm[4][2];                 // [a u][m j-pair]
#pragma unroll
        for (int v = 0; v < 4; v++) {
            float4 e4 = *(const float4*)&eth [qg * 4 + v][ty * 4];
            float4 f4 = *(const float4*)&ecth[qg * 4 + v][tx * 4];
            en[v][0] = e4.x; en[v][1] = e4.y; en[v][2] = e4.z; en[v][3] = e4.w;
            fm[v][0] = f32x2{f4.x, f4.y};
            fm[v][1] = f32x2{f4.z, f4.w};
        }
#pragma unroll
        for (int i = 0; i < 4; i++)
#pragma unroll
            for (int jp = 0; jp < 2; jp++) {
                const f32x2 one = (f32x2)1.f;
                f32x2 q0 = fma2((f32x2)en[0][i], fm[0][jp], one);
                f32x2 q1 = fma2((f32x2)en[1][i], fm[1][jp], one);
                f32x2 q2 = fma2((f32x2)en[2][i], fm[2][jp], one);
                f32x2 q3 = fma2((f32x2)en[3][i], fm[3][jp], one);
                f32x2 q01 = q0 * q1, q23 = q2 * q3;
                f32x2 n01 = fma2((f32x2)ag.x, q1, (f32x2)ag.y * q0);
                f32x2 n23 = fma2((f32x2)ag.z, q3, (f32x2)ag.w * q2);
                f32x2 N   = fma2(n01, q23, n23 * q01);
                f32x2 D   = q01 * q23;              // <= 2^121, no overflow
                f32x2 r;
                r.x = __builtin_amdgcn_rcpf(D.x);
                r.y = __builtin_amdgcn_rcpf(D.y);
                acc2[i][jp] = fma2(N, r, acc2[i][jp]);
            }
    }

    // partial_h = 0.5*sagg_h - acc_h ; 4-way merge via LDS (stride 17: conflict-free)
    const float base = 0.5f * sagg;
    float* xb = (float*)ect;             // reuse (3*256*17 floats = 52 KB < 69.6 KB)
    __syncthreads();                     // all LDS reads of et/ect complete
    if (h != 0) {
        float* w = xb + ((size_t)(h - 1) * 256 + u) * 17;
#pragma unroll
        for (int i = 0; i < 4; i++)
#pragma unroll
            for (int jp = 0; jp < 2; jp++) {
                w[i * 4 + jp * 2 + 0] = base - acc2[i][jp].x;
                w[i * 4 + jp * 2 + 1] = base - acc2[i][jp].y;
            }
    }
    __syncthreads();
    if (h == 0) {
        const float* x1 = xb + (size_t)u * 17;
        const float* x2 = xb + ((size_t)256 + u) * 17;
        const float* x3 = xb + ((size_t)512 + u) * 17;
#pragma unroll
        for (int i = 0; i < 4; i++) {
            f32x4 v;
            v.x = ((base - acc2[i][0].x) + x1[i * 4 + 0]) + (x2[i * 4 + 0] + x3[i * 4 + 0]);
            v.y = ((base - acc2[i][0].y) + x1[i * 4 + 1]) + (x2[i * 4 + 1] + x3[i * 4 + 1]);
            v.z = ((base - acc2[i][1].x) + x1[i * 4 + 2]) + (x2[i * 4 + 2] + x3[i * 4 + 2]);
            v.w = ((base - acc2[i][1].y) + x1[i * 4 + 3]) + (x2[i * 4 + 3] + x3[i * 4 + 3]);
            __builtin_nontemporal_store(v,
                (f32x4*)(out + ((size_t)(b * 512 + n0 + ty * 4 + i) * 512) + m0 + tx * 4));
        }
    }
}

extern "C" void kernel_launch(void* const* d_in, const int* in_sizes, int n_in,
                              void* d_out, int out_size, void* d_ws, size_t ws_size,
                              hipStream_t stream) {
    const float* data = (const float*)d_in[0];
    const float* crit = (const float*)d_in[1];
    const float* Wl   = (const float*)d_in[2];
    const float* bl   = (const float*)d_in[3];
    const float* Wr   = (const float*)d_in[4];
    const float* br   = (const float*)d_in[5];
    const float* agg  = (const float*)d_in[6];
    float* out = (float*)d_out;

    // ws layout: Ed bf16 [256][2048] (1 MB) | Ec (1 MB)
    ushort* eplanes = (ushort*)d_ws;

    // proj (inline W transpose): 4 col-tiles x 128 row-tiles = 512 blocks
    proj_mfma_kernel<<<dim3(512), 256, 0, stream>>>(data, crit, Wl, bl, Wr, br, eplanes);

    // tanh: (8 m x 8 n) x 4 b = 256 blocks x 1024 threads; writes out directly
    tanh_reduce_kernel<<<dim3(8, 8, 4), 1024, 0, stream>>>(eplanes, agg, out);
}